// Round 3
// baseline (1791.808 us; speedup 1.0000x reference)
//
#include <hip/hip_runtime.h>
#include <math.h>

#define NUM_CODES 8192
#define DIM 256
#define NROWS 32768            // 32 * 32 * 32
#define NELEM (NROWS * DIM)    // 8388608

// d_out layout (fp32 elements): loss | quantized | perplexity | indices
#define OUT_LOSS 0
#define OUT_Q 1
#define OUT_PERP (1 + NELEM)
#define OUT_IDX (2 + NELEM)

// workspace layout (bytes)
#define WS_A2 0                // 32768 f32  (128 KB)
#define WS_IDX 131072          // 32768 i32  (128 KB)
#define WS_COUNTS 262144       // 8192 i32   (32 KB)
#define WS_PART 294912         // 8192 f64   (64 KB)
#define NQBLK (NELEM / 1024)   // 8192 quant blocks

// ---------------- A[n] = np.sum(flat[n]**2) with exact numpy pairwise fp32 ----------------
// numpy pairwise_sum for n=256: split into two 128-halves; each half uses 8
// interleaved accumulators r[j] = sum_{i%8==j} a[i] (sequential), combined as
// ((r0+r1)+(r2+r3))+((r4+r5)+(r6+r7)); halves added last. All fp32, no FMA.
__global__ __launch_bounds__(256) void k_a2(const float* __restrict__ in,
                                            float* __restrict__ a2) {
  const int n = (blockIdx.x << 8) + threadIdx.x;
  const int b = n >> 10, hw = n & 1023;
  const float* p = in + (((size_t)b) << 18) + hw;  // p[c<<10] = x[n][c]
  float s[2];
#pragma unroll
  for (int h = 0; h < 2; ++h) {
    const int c0 = h << 7;
    float r[8];
#pragma unroll
    for (int j = 0; j < 8; ++j) {
      const float v = p[(size_t)(c0 + j) << 10];
      r[j] = __fmul_rn(v, v);
    }
    for (int i = 8; i < 128; i += 8) {
#pragma unroll
      for (int j = 0; j < 8; ++j) {
        const float v = p[(size_t)(c0 + i + j) << 10];
        r[j] = __fadd_rn(r[j], __fmul_rn(v, v));
      }
    }
    s[h] = __fadd_rn(__fadd_rn(__fadd_rn(r[0], r[1]), __fadd_rn(r[2], r[3])),
                     __fadd_rn(__fadd_rn(r[4], r[5]), __fadd_rn(r[6], r[7])));
  }
  a2[n] = __fadd_rn(s[0], s[1]);
}

// ---------------- fused distances + argmin, fp32-reference-emulating ----------------
// d_k = fl( A_row - 2*G_k ), G_k = sequential ascending-c fused-FMA dot.
// (The ||c||^2 term is < ulp(A)/2 for every row -> annihilated by the fp32 add;
//  ties on the coarse ulp(A)~3e-5 grid are broken by LOWEST index, like np.argmin.)
// block = 256 threads, 64 rows/block; thread tile 8 rows x 8 codes.
__global__ __launch_bounds__(256, 2) void k_argmin(const float* __restrict__ in,
                                                   const float* __restrict__ cbk,
                                                   const float* __restrict__ a2,
                                                   int* __restrict__ idx_out,
                                                   float* __restrict__ idx_out_f) {
  __shared__ __align__(16) float xs[32 * 68];   // [ck][64 rows + pad4]
  __shared__ __align__(16) float cs[32 * 260];  // [ck][256 codes + pad4]
  const int tid = threadIdx.x;
  const int trow = tid >> 5;  // 0..7 -> rows trow*8..+7
  const int tcol = tid & 31;  // 0..31 -> codes tcol*4..+3 and +128..
  const int r0 = blockIdx.x << 6;
  const int bb = r0 >> 10;   // batch
  const int hw0 = r0 & 1023; // h*32+w base

  float ar[8];
#pragma unroll
  for (int r = 0; r < 8; ++r) ar[r] = a2[r0 + (trow << 3) + r];

  float bd[8];
  int bi[8];
#pragma unroll
  for (int r = 0; r < 8; ++r) { bd[r] = 3.402823466e+38f; bi[r] = 0x7fffffff; }

  const int s_ck = tid >> 3;
  const int s_w4 = (tid & 7) << 2;

  for (int kb = 0; kb < NUM_CODES; kb += 256) {
    float acc[8][8];
#pragma unroll
    for (int r = 0; r < 8; ++r)
#pragma unroll
      for (int q = 0; q < 8; ++q) acc[r][q] = 0.f;

    for (int cb = 0; cb < DIM; cb += 32) {
      // stage x chunk: 32 channels x 64 rows (coalesced in NCHW)
      {
        const float* src = in + (((size_t)(bb * DIM + cb + s_ck)) << 10) + hw0 + s_w4;
        const float4 a = *(const float4*)(src);
        const float4 b = *(const float4*)(src + 32);
        *(float4*)&xs[s_ck * 68 + s_w4] = a;
        *(float4*)&xs[s_ck * 68 + s_w4 + 32] = b;
      }
      // stage code chunk transposed: cs[ck][k]
#pragma unroll
      for (int i = 0; i < 8; ++i) {
        const int fid = tid + (i << 8);
        const int k = fid >> 3;
        const int c4 = (fid & 7) << 2;
        const float4 cv = *(const float4*)(cbk + (((size_t)(kb + k)) << 8) + cb + c4);
        cs[(c4 + 0) * 260 + k] = cv.x;
        cs[(c4 + 1) * 260 + k] = cv.y;
        cs[(c4 + 2) * 260 + k] = cv.z;
        cs[(c4 + 3) * 260 + k] = cv.w;
      }
      __syncthreads();
      // IMPORTANT: ck ascending + single accumulator + fused fmaf == sequential
      // ascending-c FMA chain, emulating the BLAS sgemm k-accumulation.
#pragma unroll 4
      for (int ck = 0; ck < 32; ++ck) {
        const float4 xa = *(const float4*)&xs[ck * 68 + (trow << 3)];
        const float4 xb = *(const float4*)&xs[ck * 68 + (trow << 3) + 4];
        const float4 ca = *(const float4*)&cs[ck * 260 + (tcol << 2)];
        const float4 cb2 = *(const float4*)&cs[ck * 260 + (tcol << 2) + 128];
        const float xv[8] = {xa.x, xa.y, xa.z, xa.w, xb.x, xb.y, xb.z, xb.w};
        const float cv[8] = {ca.x, ca.y, ca.z, ca.w, cb2.x, cb2.y, cb2.z, cb2.w};
#pragma unroll
        for (int r = 0; r < 8; ++r)
#pragma unroll
          for (int q = 0; q < 8; ++q) acc[r][q] = __builtin_fmaf(xv[r], cv[q], acc[r][q]);
      }
      __syncthreads();
    }
    // fold: d = fl(A - 2*G), strict < with ascending kk -> np.argmin semantics
#pragma unroll
    for (int g = 0; g < 2; ++g)
#pragma unroll
      for (int j = 0; j < 4; ++j) {
        const int kk = kb + (tcol << 2) + j + (g << 7);
#pragma unroll
        for (int r = 0; r < 8; ++r) {
          const float d = __fadd_rn(ar[r], __fmul_rn(-2.0f, acc[r][(g << 2) + j]));
          if (d < bd[r]) { bd[r] = d; bi[r] = kk; }
        }
      }
  }

  // cross-thread reduction: 32 candidates per row, equal-d -> lower index
  __syncthreads();
  float2* red = (float2*)cs;
#pragma unroll
  for (int r = 0; r < 8; ++r)
    red[((trow << 3) + r) * 32 + tcol] = make_float2(bd[r], __int_as_float(bi[r]));
  __syncthreads();
  if (tid < 64) {
    float bestd = 3.402823466e+38f;
    int besti = 0x7fffffff;
    for (int c = 0; c < 32; ++c) {
      const float2 v = red[tid * 32 + c];
      const int vi = __float_as_int(v.y);
      if (v.x < bestd || (v.x == bestd && vi < besti)) { bestd = v.x; besti = vi; }
    }
    const int n = r0 + tid;
    idx_out[n] = besti;
    idx_out_f[n] = (float)besti;
  }
}

// ---------------- quantized output + loss partials ----------------
__global__ __launch_bounds__(256) void k_quant(const float* __restrict__ in,
                                               const float* __restrict__ cbk,
                                               const int* __restrict__ idx,
                                               float* __restrict__ outq,
                                               double* __restrict__ partials) {
  const int tid = threadIdx.x;
  const int e = (blockIdx.x << 10) + (tid << 2);
  const int bc = e >> 10;
  const int hw = e & 1023;
  const int b = bc >> 8;
  const int c = bc & 255;
  const int nbase = (b << 10) + hw;
  const float4 x = *(const float4*)(in + e);
  const float xv[4] = {x.x, x.y, x.z, x.w};
  double ls = 0.0;
  float o[4];
#pragma unroll
  for (int j = 0; j < 4; ++j) {
    const int qi = idx[nbase + j];
    const float q = cbk[((size_t)qi << 8) + c];
    const float diff = q - xv[j];
    o[j] = xv[j] + diff;  // straight-through numerics: x + (q - x)
    ls += (double)diff * (double)diff;
  }
  outq[e] = o[0];
  outq[e + 1] = o[1];
  outq[e + 2] = o[2];
  outq[e + 3] = o[3];
#pragma unroll
  for (int off = 32; off >= 1; off >>= 1) ls += __shfl_down(ls, off, 64);
  __shared__ double wsum[4];
  const int lane = tid & 63, wid = tid >> 6;
  if (lane == 0) wsum[wid] = ls;
  __syncthreads();
  if (tid == 0) partials[blockIdx.x] = wsum[0] + wsum[1] + wsum[2] + wsum[3];
}

// ---------------- code histogram ----------------
__global__ __launch_bounds__(256) void k_counts(const int* __restrict__ idx,
                                                int* __restrict__ counts) {
  const int n = (blockIdx.x << 8) + threadIdx.x;
  atomicAdd(&counts[idx[n]], 1);
}

// ---------------- loss + perplexity ----------------
__global__ __launch_bounds__(256) void k_finalize(const double* __restrict__ partials,
                                                  const int* __restrict__ counts,
                                                  float* __restrict__ out_loss,
                                                  float* __restrict__ out_perp) {
  const int tid = threadIdx.x;
  double sl = 0.0, se = 0.0;
  for (int i = tid; i < NQBLK; i += 256) sl += partials[i];
  for (int k = tid; k < NUM_CODES; k += 256) {
    const double p = (double)counts[k] / 32768.0;
    se += p * log(p + 1e-10);
  }
#pragma unroll
  for (int off = 32; off >= 1; off >>= 1) {
    sl += __shfl_down(sl, off, 64);
    se += __shfl_down(se, off, 64);
  }
  __shared__ double sL[4], sE[4];
  const int lane = tid & 63, wid = tid >> 6;
  if (lane == 0) { sL[wid] = sl; sE[wid] = se; }
  __syncthreads();
  if (tid == 0) {
    const double L = sL[0] + sL[1] + sL[2] + sL[3];
    const double E = sE[0] + sE[1] + sE[2] + sE[3];
    const double m = L / (double)NELEM;
    *out_loss = (float)(m + 0.6 * m);  // q_latent + 0.6 * e_latent
    *out_perp = (float)exp(-E);
  }
}

extern "C" void kernel_launch(void* const* d_in, const int* in_sizes, int n_in,
                              void* d_out, int out_size, void* d_ws, size_t ws_size,
                              hipStream_t stream) {
  const float* in = (const float*)d_in[0];
  const float* cbk = (const float*)d_in[1];
  float* out = (float*)d_out;
  char* ws = (char*)d_ws;
  float* a2 = (float*)(ws + WS_A2);
  int* idx = (int*)(ws + WS_IDX);
  int* counts = (int*)(ws + WS_COUNTS);
  double* partials = (double*)(ws + WS_PART);

  hipMemsetAsync(counts, 0, NUM_CODES * sizeof(int), stream);
  k_a2<<<NROWS / 256, 256, 0, stream>>>(in, a2);
  k_argmin<<<NROWS / 64, 256, 0, stream>>>(in, cbk, a2, idx, out + OUT_IDX);
  k_counts<<<NROWS / 256, 256, 0, stream>>>(idx, counts);
  k_quant<<<NELEM / 1024, 256, 0, stream>>>(in, cbk, idx, out + OUT_Q, partials);
  k_finalize<<<1, 256, 0, stream>>>(partials, counts, out + OUT_LOSS, out + OUT_PERP);
}